// Round 12
// baseline (124.707 us; speedup 1.0000x reference)
//
#include <hip/hip_runtime.h>
#include <hip/hip_bf16.h>
#include <stdint.h>
#include <stddef.h>

#define BATCH 4096
#define INF   1024
#define OUTF  1024
#define KDIM  8192            // 1024 in-features * 8 spline bases
#define KS    4               // split-K factor
#define KSL   (KDIM / KS)     // 2048 per slice
#define BK    64
#define NT    (KSL / BK)      // 32 K-tiles per block
#define NK32  (KDIM / 32)     // 256 k32-blocks

typedef __attribute__((ext_vector_type(8)))  short           short8;
typedef __attribute__((ext_vector_type(8)))  unsigned short  ushort8;
typedef __attribute__((ext_vector_type(4)))  float           f32x4;

__device__ constexpr float knot(int j) { return (float)(j - 3) * 0.4f - 1.0f; }

// ---------------------------------------------------------------------------
// Kernel 1: fused prep.
// Blocks [0,16384): B-spline bases -> A (row-major [b][k], k=i*8+g).
// Blocks [16384,20480): weights fp32 -> bf16 in FRAGMENT-NATIVE layout
//   W2[o16][k32][lr(16)][lk(4)][8 elems], o=o16*16+lr, k=k32*32+lk*8,
//   so a GEMM wave's B-fragment load is one contiguous 1024-B block.
// ---------------------------------------------------------------------------
__global__ __launch_bounds__(256) void kan_prep(const float* __restrict__ x,
                                                short8* __restrict__ A,
                                                const f32x4* __restrict__ w,
                                                ushort8* __restrict__ W2) {
    const int blk = blockIdx.x;
    if (blk < (BATCH * INF) / 256) {
        size_t idx = (size_t)blk * 256 + threadIdx.x;
        float xv = x[idx];

        float b[11];
#pragma unroll
        for (int j = 0; j < 11; ++j)
            b[j] = (xv >= knot(j) && xv < knot(j + 1)) ? 1.0f : 0.0f;

#pragma unroll
        for (int k = 1; k <= 3; ++k) {
#pragma unroll
            for (int j = 0; j + k < 11; ++j) {
                float left  = (xv - knot(j))         * (1.0f / (knot(j + k)     - knot(j)));
                float right = (knot(j + k + 1) - xv) * (1.0f / (knot(j + k + 1) - knot(j + 1)));
                b[j] = left * b[j] + right * b[j + 1];
            }
        }

        union { short8 v; unsigned short u[8]; } pk;
#pragma unroll
        for (int g = 0; g < 8; ++g) {
            __hip_bfloat16 h = __float2bfloat16(b[g]);
            pk.u[g] = *reinterpret_cast<unsigned short*>(&h);
        }
        A[idx] = pk.v;
    } else {
        // weight convert + permute: thread -> (o, k8) with 8 consecutive k
        size_t idx = (size_t)(blk - (BATCH * INF) / 256) * 256 + threadIdx.x;
        const int o  = (int)(idx >> 10);           // KDIM/8 = 1024 k8 per o
        const int k8 = (int)(idx & 1023);
        f32x4 a = w[idx * 2];
        f32x4 c = w[idx * 2 + 1];
        float t[8] = {a[0], a[1], a[2], a[3], c[0], c[1], c[2], c[3]};
        union { ushort8 v; unsigned short u[8]; } pk;
#pragma unroll
        for (int g = 0; g < 8; ++g) {
            __hip_bfloat16 h = __float2bfloat16(t[g]);
            pk.u[g] = *reinterpret_cast<unsigned short*>(&h);
        }
        const int o16 = o >> 4, lr = o & 15;
        const int k32 = k8 >> 2, lk = k8 & 3;
        W2[((size_t)(o16 * NK32 + k32) << 6) + (lr << 2) + lk] = pk.v;
    }
}

// ---------------------------------------------------------------------------
// Kernel 2: bf16 GEMM, 256x256 tile, BK=64, split-K=4.
// A: LDS double-buffer (2x32 KiB), zero-conflict XOR swizzle (r10-verified).
// B: DIRECT from global W2 — one coalesced 1024-B load per (fj,kk) per wave,
//    L1-served (32 KB/tile slice, 4x intra-CU reuse). Removes B from the LDS
//    pipe: per-tile LDS traffic 320 KB -> 160 KB.
// 1024 threads = 16 waves (4M x 4N, 64x64/wave), mfma_f32_16x16x32_bf16.
// Distance-1 A-prefetch; one vmcnt(0)+barrier per K-tile.
// mode 0: bf16 split-K partials; mode 1: fp32 atomicAdd fallback.
// ---------------------------------------------------------------------------
__device__ __forceinline__ void gload16(const void* g, void* l) {
    __builtin_amdgcn_global_load_lds((const __attribute__((address_space(1))) void*)g,
                                     (__attribute__((address_space(3))) void*)l,
                                     16, 0, 0);
}

#define MFMA(a, b, c) __builtin_amdgcn_mfma_f32_16x16x32_bf16((a), (b), (c), 0, 0, 0)

__global__ __launch_bounds__(1024, 1) void kan_gemm(const __hip_bfloat16* __restrict__ A,
                                                    const ushort8* __restrict__ W2,
                                                    __hip_bfloat16* __restrict__ Pb,
                                                    float* __restrict__ outC,
                                                    int mode) {
    __shared__ __hip_bfloat16 sA[2][256 * 64];   // 2 x 32 KiB

    const int tid  = threadIdx.x;
    const int orig = blockIdx.x;
    const int sb   = (orig & 7) * 32 + (orig >> 3);   // XCD chunk swizzle (256%8==0)
    const int bm   = sb >> 4;            // 0..15
    const int bn   = (sb >> 2) & 3;      // 0..3
    const int ks   = sb & 3;             // 0..3
    const int m0   = bm << 8;
    const int n0   = bn << 8;
    const int k0   = ks * KSL;

    // A staging: thread t -> rows (t>>3)+r*128, 16B slot (t&7); dest linear.
    // Source col pre-swizzled: LDS[row][s] = G[row][s ^ (row&7)].
    const int srow = tid >> 3;                                // 0..127
    const int scol = (((tid & 7) ^ (srow & 7)) << 3);         // elems
    const __hip_bfloat16* gA = A + (size_t)(m0 + srow) * KDIM + k0 + scol;
    const int t8 = tid * 8;

#define GLA(buf, kt, r) gload16(gA + (size_t)(kt) * BK + (size_t)((r) * 128) * KDIM, \
                                &sA[buf][(r) * 8192 + t8])

    // compute: wave w -> rows [(w>>2)*64,+64), cols [(w&3)*64,+64)
    const int w    = tid >> 6;
    const int lane = tid & 63;
    const int wr   = w >> 2;             // 0..3
    const int wc   = w & 3;              // 0..3
    const int lr   = lane & 15;
    const int lk   = lane >> 4;          // 0..3
    const int ar0  = (wr << 6) + lr;     // + fi*16
    const int rx   = lr & 7;             // read-side XOR (row&7)

    // B direct-global: block index (in 64-ushort8 units) for (fj,kk) at tile t:
    //   bidx = ((n0>>4) + wc*4 + fj)*NK32 + (k0>>5) + 2t + kk ; lane off lr*4+lk
    const ushort8* Wbase = W2 + (((size_t)((n0 >> 4) + (wc << 2)) * NK32 + (k0 >> 5)) << 6)
                              + (lr << 2) + lk;
    // per fj stride: NK32<<6 ; per (t,kk) stride: 64

    f32x4 acc[4][4];
#pragma unroll
    for (int i = 0; i < 4; ++i)
#pragma unroll
        for (int j = 0; j < 4; ++j)
            acc[i][j] = (f32x4){0.0f, 0.0f, 0.0f, 0.0f};

    // --- prologue: stage A tile 0 into buf0; drain; barrier ---
    GLA(0, 0, 0); GLA(0, 0, 1);
    asm volatile("s_waitcnt vmcnt(0)" ::: "memory");
    __builtin_amdgcn_s_barrier();

#pragma unroll 1
    for (int t = 0; t < NT; ++t) {
        const int buf = t & 1;
        const __hip_bfloat16* tA = &sA[buf][0];

        // prefetch A tile t+1 (issued a full epoch early)
        if (t + 1 < NT) {
            GLA(buf ^ 1, t + 1, 0); GLA(buf ^ 1, t + 1, 1);
        }
        __builtin_amdgcn_sched_barrier(0);   // pin A-stage issue at epoch top

        // epoch body: 2 kk steps; per step 4 ds_read_b128 (A) + 4 coalesced
        // global b128 (B) + 16 MFMA. A phys slot = (4kk+lk)^(lr&7): 0 conflicts.
#pragma unroll
        for (int kk = 0; kk < 2; ++kk) {
            const int ph = (((kk << 2) | lk) ^ rx) << 3;   // A elem offset in row
            const ushort8* wp = Wbase + (((size_t)t << 1) + kk) * 64;
            short8 af[4]; ushort8 bf[4];
#pragma unroll
            for (int fj = 0; fj < 4; ++fj)
                bf[fj] = wp[(size_t)fj * (NK32 << 6)];
#pragma unroll
            for (int fi = 0; fi < 4; ++fi)
                af[fi] = *reinterpret_cast<const short8*>(tA + (ar0 + fi * 16) * BK + ph);
#pragma unroll
            for (int fi = 0; fi < 4; ++fi)
#pragma unroll
                for (int fj = 0; fj < 4; ++fj)
                    acc[fi][fj] = MFMA(af[fi], (short8)bf[fj], acc[fi][fj]);
        }

        // --- epoch boundary: A staging landed (issued ~2500 cy ago) ---
        asm volatile("s_waitcnt vmcnt(0)" ::: "memory");
        __builtin_amdgcn_s_barrier();
    }
#undef GLA

    // --- epilogue: 16x16 C/D layout: col = lane&15, row = (lane>>4)*4 + reg ---
    if (mode == 0) {
        __hip_bfloat16* dst = Pb + (size_t)ks * BATCH * OUTF;
#pragma unroll
        for (int fi = 0; fi < 4; ++fi) {
#pragma unroll
            for (int fj = 0; fj < 4; ++fj) {
                __hip_bfloat16* cp = dst
                    + (size_t)(m0 + (wr << 6) + fi * 16 + lk * 4) * OUTF
                    + (n0 + (wc << 6) + fj * 16 + lr);
#pragma unroll
                for (int r = 0; r < 4; ++r)
                    cp[(size_t)r * OUTF] = __float2bfloat16(acc[fi][fj][r]);
            }
        }
    } else {
#pragma unroll
        for (int fi = 0; fi < 4; ++fi) {
#pragma unroll
            for (int fj = 0; fj < 4; ++fj) {
                float* cp = outC + (size_t)(m0 + (wr << 6) + fi * 16 + lk * 4) * OUTF
                                 + (n0 + (wc << 6) + fj * 16 + lr);
#pragma unroll
                for (int r = 0; r < 4; ++r)
                    atomicAdd(cp + (size_t)r * OUTF, acc[fi][fj][r]);
            }
        }
    }
}

// ---------------------------------------------------------------------------
// Kernel 3: split-K reduce  out = sum of 4 bf16 partials (fp32 accumulate).
// ---------------------------------------------------------------------------
__global__ __launch_bounds__(256) void kan_reduce(const ushort8* __restrict__ Pb,
                                                  f32x4* __restrict__ out) {
    size_t i = (size_t)blockIdx.x * 256 + threadIdx.x;   // per 8 elems
    const size_t stride = (size_t)BATCH * OUTF / 8;
    ushort8 p0 = Pb[i];
    ushort8 p1 = Pb[i + stride];
    ushort8 p2 = Pb[i + 2 * stride];
    ushort8 p3 = Pb[i + 3 * stride];

    f32x4 lo, hi;
#pragma unroll
    for (int e = 0; e < 8; ++e) {
        union { unsigned int u; float f; } c0, c1, c2, c3;
        c0.u = (unsigned int)p0[e] << 16;
        c1.u = (unsigned int)p1[e] << 16;
        c2.u = (unsigned int)p2[e] << 16;
        c3.u = (unsigned int)p3[e] << 16;
        float s = (c0.f + c1.f) + (c2.f + c3.f);
        if (e < 4) lo[e] = s; else hi[e - 4] = s;
    }
    out[i * 2]     = lo;
    out[i * 2 + 1] = hi;
}

// ---------------------------------------------------------------------------
extern "C" void kernel_launch(void* const* d_in, const int* in_sizes, int n_in,
                              void* d_out, int out_size, void* d_ws, size_t ws_size,
                              hipStream_t stream) {
    const float* x = (const float*)d_in[0];       // (4096, 1024) fp32
    const float* w = (const float*)d_in[1];       // (1024, 1024, 8) fp32
    float* out = (float*)d_out;                   // (4096, 1024) fp32

    const size_t offW  = (size_t)BATCH * KDIM * 2;           // Abf: 64 MiB
    const size_t offP  = offW + (size_t)OUTF * KDIM * 2;     // W2:  +16 MiB
    const size_t needP = offP + (size_t)KS * BATCH * OUTF * 2; // +32 MiB bf16 partials

    __hip_bfloat16* Abf = (__hip_bfloat16*)d_ws;
    ushort8*        W2  = (ushort8*)((char*)d_ws + offW);
    __hip_bfloat16* Pb  = (__hip_bfloat16*)((char*)d_ws + offP);
    const bool partials = (ws_size >= needP);

    const int prepGrid = (BATCH * INF) / 256 + (OUTF * KDIM / 8) / 256;  // 20480
    kan_prep<<<prepGrid, 256, 0, stream>>>(x, (short8*)Abf, (const f32x4*)w, W2);

    const int grid = (BATCH / 256) * (OUTF / 256) * KS;     // 256
    if (partials) {
        kan_gemm<<<grid, 1024, 0, stream>>>(Abf, W2, Pb, out, 0);
        kan_reduce<<<(BATCH * OUTF / 8) / 256, 256, 0, stream>>>((const ushort8*)Pb, (f32x4*)out);
    } else {
        hipMemsetAsync(out, 0, (size_t)BATCH * OUTF * sizeof(float), stream);
        kan_gemm<<<grid, 1024, 0, stream>>>(Abf, W2, Pb, out, 1);
    }
}